// Round 1
// baseline (16046.225 us; speedup 1.0000x reference)
//
#include <hip/hip_runtime.h>
#include <stdint.h>

#define B_   64
#define T_   512
#define EI_  1024
#define EO_  1024

typedef __attribute__((ext_vector_type(4))) float  f32x4;
typedef __attribute__((ext_vector_type(8))) short  s16x8;
typedef __attribute__((ext_vector_type(4))) unsigned short u16x4;

__device__ __forceinline__ unsigned short f2bf(float f) {
    union { float f; unsigned int u; } v; v.f = f;
    unsigned int r = v.u + 0x7FFFu + ((v.u >> 16) & 1u);
    return (unsigned short)(r >> 16);
}

// ---- prep: transpose+convert weights to bf16 [N][K], init hbf parity-1 = bf16(h0), zero flags ----
__global__ void prep_kernel(const float* __restrict__ wxh, const float* __restrict__ whf,
                            const float* __restrict__ h0,
                            unsigned short* __restrict__ wxhT, unsigned short* __restrict__ whfT,
                            unsigned short* __restrict__ hbf1, unsigned int* __restrict__ flags)
{
    int idx = blockIdx.x * blockDim.x + threadIdx.x;
    if (idx < 256) flags[idx] = 0u;
    const int NW = EI_ * EO_;
    if (idx < NW) {
        int n = idx & (EO_ - 1);
        int k = idx >> 10;
        wxhT[(size_t)n * EI_ + k] = f2bf(wxh[(size_t)k * EO_ + n]);
        whfT[(size_t)n * EO_ + k] = f2bf(whf[(size_t)k * EO_ + n]);
    } else {
        int j = idx - NW;
        if (j < B_ * EO_) hbf1[j] = f2bf(h0[j]);
    }
}

// ---- kernel 1: G = tanh(X @ wxh) written into the outs region of d_out ----
// 128x128 tile, BK=64, 4 waves (2x2), 16x16x32 bf16 MFMA, reg-staged fp32->bf16 A.
__launch_bounds__(256, 2)
__global__ void gemm_g_kernel(const float* __restrict__ X,
                              const unsigned short* __restrict__ WT,  // wxh^T bf16 [N][K]
                              float* __restrict__ out)
{
    __shared__ alignas(16) unsigned short As[128 * 72];   // [m][k], stride 72 (pad: 2-way banks)
    __shared__ alignas(16) unsigned short Bs[128 * 72];   // [n][k], stride 72

    const int bid = blockIdx.x;
    const int bn = bid & 7, bm = bid >> 3;
    const int m0 = bm * 128, n0 = bn * 128;
    const int tid  = threadIdx.x;
    const int lane = tid & 63, w = tid >> 6;
    const int wr = w >> 1, wc = w & 1;
    const int l15 = lane & 15, lg = lane >> 4;

    f32x4 acc[4][4] = {};

    for (int kt = 0; kt < EI_ / 64; ++kt) {
        const int k0 = kt * 64;
        // stage A: 128 rows x 64 k, fp32 -> bf16
        #pragma unroll
        for (int p = 0; p < 8; ++p) {
            int row = p * 16 + (tid >> 4);
            int kq  = tid & 15;
            f32x4 v = *(const f32x4*)(X + (size_t)(m0 + row) * EI_ + k0 + kq * 4);
            u16x4 hv;
            hv[0] = f2bf(v[0]); hv[1] = f2bf(v[1]); hv[2] = f2bf(v[2]); hv[3] = f2bf(v[3]);
            *(u16x4*)(&As[row * 72 + kq * 4]) = hv;
        }
        // stage B: 128 rows x 64 k, already bf16, contiguous 16B copies
        #pragma unroll
        for (int p = 0; p < 4; ++p) {
            int n  = p * 32 + (tid >> 3);
            int kq = tid & 7;
            s16x8 v = *(const s16x8*)(WT + (size_t)(n0 + n) * EI_ + k0 + kq * 8);
            *(s16x8*)(&Bs[n * 72 + kq * 8]) = v;
        }
        __syncthreads();
        #pragma unroll
        for (int kk = 0; kk < 2; ++kk) {
            s16x8 a[4], b[4];
            #pragma unroll
            for (int mt = 0; mt < 4; ++mt)
                a[mt] = *(const s16x8*)(&As[(wr * 64 + mt * 16 + l15) * 72 + kk * 32 + lg * 8]);
            #pragma unroll
            for (int nt = 0; nt < 4; ++nt)
                b[nt] = *(const s16x8*)(&Bs[(wc * 64 + nt * 16 + l15) * 72 + kk * 32 + lg * 8]);
            #pragma unroll
            for (int mt = 0; mt < 4; ++mt)
                #pragma unroll
                for (int nt = 0; nt < 4; ++nt)
                    acc[mt][nt] = __builtin_amdgcn_mfma_f32_16x16x32_bf16(a[mt], b[nt], acc[mt][nt], 0, 0, 0);
        }
        __syncthreads();
    }
    // epilogue: tanh, fp32 store. C/D: col = lane&15, row = (lane>>4)*4 + reg  [HW-verified]
    #pragma unroll
    for (int mt = 0; mt < 4; ++mt) {
        #pragma unroll
        for (int nt = 0; nt < 4; ++nt) {
            #pragma unroll
            for (int r = 0; r < 4; ++r) {
                int row = wr * 64 + mt * 16 + lg * 4 + r;
                int col = wc * 64 + nt * 16 + l15;
                float s = acc[mt][nt][r];
                float e = __expf(2.f * s);
                out[(size_t)(m0 + row) * EO_ + n0 + col] = 1.f - 2.f / (e + 1.f);
            }
        }
    }
}

// ---- kernel 2: sequential recurrence. 256 blocks = 4 batch-groups x 64 col-blocks.
// Each block owns a fixed [16 batch x 16 col] tile; fp32 h carried in registers;
// bf16 H shared globally (double-buffered); per-block monotonic flags, group-local polling.
__launch_bounds__(256)
__global__ void recur_kernel(const float* __restrict__ h0,
                             const unsigned short* __restrict__ whfT, // whf^T bf16 [N][K]
                             unsigned short* hbf,                     // [2][64*1024]
                             unsigned int* flags,                     // [256]
                             float* out)
{
    __shared__ alignas(16) unsigned short Ws[16 * 1032];  // W cols slice, stride 1032 (pad)
    __shared__ float Sred[4 * 256];

    const int bid = blockIdx.x;
    const int cc = bid & 63, cb = bid >> 6;
    const int tid  = threadIdx.x;
    const int lane = tid & 63, w = tid >> 6;
    const int l15 = lane & 15, lg = lane >> 4;

    // stage this block's 16 W columns into LDS once; reused for all 512 steps
    {
        int c  = tid >> 4;      // 0..15
        int kq = tid & 15;      // 0..15
        #pragma unroll
        for (int p = 0; p < 8; ++p) {
            int kk = (kq + p * 16) * 8;
            s16x8 v = *(const s16x8*)(whfT + (size_t)(cc * 16 + c) * EO_ + kk);
            *(s16x8*)(&Ws[c * 1032 + kk]) = v;
        }
    }

    const int row = tid >> 4;       // batch within group
    const int col = tid & 15;       // column within block slice
    const int b = cb * 16 + row;
    const int j = cc * 16 + col;
    float h = h0[(size_t)b * EO_ + j];

    const int grpbase = cb * 64;
    const unsigned long long FULL = ~0ULL;

    __syncthreads();

    for (int t = 0; t < T_; ++t) {
        if (t > 0) {
            unsigned int want = (unsigned int)t;
            int spins = 0;
            for (;;) {
                unsigned int f = __hip_atomic_load(&flags[grpbase + lane],
                                                   __ATOMIC_RELAXED, __HIP_MEMORY_SCOPE_AGENT);
                if (__ballot(f >= want) == FULL) break;
                if (++spins > (1 << 16)) break;   // safety valve: never hang
            }
            __threadfence();   // acquire: invalidate stale L1/L2 before reading peers' H
        }
        // S = H_old @ whf, K split 4 ways across waves
        const unsigned short* hOld = hbf + (size_t)((t & 1) ^ 1) * (B_ * EO_);
        f32x4 acc = {0.f, 0.f, 0.f, 0.f};
        const int koff = w * 256;
        #pragma unroll
        for (int kk = 0; kk < 8; ++kk) {
            int k = koff + kk * 32 + lg * 8;
            s16x8 a  = *(const s16x8*)(hOld + (size_t)(cb * 16 + l15) * EO_ + k);
            s16x8 bb = *(const s16x8*)(&Ws[l15 * 1032 + k]);
            acc = __builtin_amdgcn_mfma_f32_16x16x32_bf16(a, bb, acc, 0, 0, 0);
        }
        #pragma unroll
        for (int r = 0; r < 4; ++r)
            Sred[w * 256 + (lg * 4 + r) * 16 + l15] = acc[r];
        __syncthreads();

        float s = Sred[tid] + Sred[256 + tid] + Sred[512 + tid] + Sred[768 + tid];
        float fg = 1.f / (1.f + __expf(-s));
        size_t oidx = ((size_t)b * T_ + t) * EO_ + j;
        float g = out[oidx];             // g_t written by gemm kernel
        h = (1.f - fg) * h + fg * g;
        out[oidx] = h;                   // overwrite in place with h_t
        hbf[(size_t)(t & 1) * (B_ * EO_) + (size_t)b * EO_ + j] = f2bf(h);
        __syncthreads();

        if (tid == 0) {
            __threadfence();             // release: make H_t visible agent-wide
            __hip_atomic_store(&flags[grpbase + cc], (unsigned int)(t + 1),
                               __ATOMIC_RELAXED, __HIP_MEMORY_SCOPE_AGENT);
        }
    }
    // final hidden state
    out[(size_t)B_ * T_ * EO_ + (size_t)b * EO_ + j] = h;
}

extern "C" void kernel_launch(void* const* d_in, const int* in_sizes, int n_in,
                              void* d_out, int out_size, void* d_ws, size_t ws_size,
                              hipStream_t stream)
{
    const float* x   = (const float*)d_in[0];
    const float* h0  = (const float*)d_in[1];
    const float* wxh = (const float*)d_in[2];
    const float* whf = (const float*)d_in[3];
    float* out = (float*)d_out;

    char* ws = (char*)d_ws;
    unsigned short* whfT  = (unsigned short*)(ws);
    unsigned short* wxhT  = (unsigned short*)(ws + (size_t)2 * 1024 * 1024);
    unsigned short* hbf   = (unsigned short*)(ws + (size_t)4 * 1024 * 1024);        // 2 x 64x1024 bf16
    unsigned int*   flags = (unsigned int*)  (ws + (size_t)4 * 1024 * 1024 + 512 * 1024);

    // prep covers 1M transpose items + 64K h0 items exactly: 4352 * 256 = 1,114,112
    prep_kernel<<<4352, 256, 0, stream>>>(wxh, whf, h0, wxhT, whfT, hbf + B_ * EO_, flags);
    gemm_g_kernel<<<2048, 256, 0, stream>>>(x, wxhT, out);
    recur_kernel<<<256, 256, 0, stream>>>(h0, whfT, hbf, flags, out);
}

// Round 2
// 4494.960 us; speedup vs baseline: 3.5698x; 3.5698x over previous
//
#include <hip/hip_runtime.h>
#include <stdint.h>

#define B_   64
#define T_   512
#define EI_  1024
#define EO_  1024

typedef __attribute__((ext_vector_type(4))) float  f32x4;
typedef __attribute__((ext_vector_type(8))) short  s16x8;
typedef __attribute__((ext_vector_type(4))) unsigned short u16x4;

__device__ __forceinline__ unsigned short f2bf(float f) {
    union { float f; unsigned int u; } v; v.f = f;
    unsigned int r = v.u + 0x7FFFu + ((v.u >> 16) & 1u);
    return (unsigned short)(r >> 16);
}

// ---- prep: LDS tile-transpose both weight matrices to bf16 [N][K]; init hbf parity-1; zero flags ----
// grid: 512 blocks x 256 thr. bid&1 selects matrix; tile = bid>>1 (16x16 tiles of 64x64).
__global__ void prep_kernel(const float* __restrict__ wxh, const float* __restrict__ whf,
                            const float* __restrict__ h0,
                            unsigned short* __restrict__ wxhT, unsigned short* __restrict__ whfT,
                            unsigned short* __restrict__ hbf1, unsigned int* __restrict__ flags)
{
    __shared__ unsigned short Ts[64][72];
    const int bid = blockIdx.x;
    const float* src = (bid & 1) ? whf : wxh;
    unsigned short* dst = (bid & 1) ? whfT : wxhT;
    const int tile = bid >> 1;                  // 0..255
    const int k0 = (tile >> 4) * 64, n0 = (tile & 15) * 64;
    const int tid = threadIdx.x;

    #pragma unroll
    for (int it = 0; it < 4; ++it) {            // read 64x64 f32, coalesced rows
        int r  = it * 16 + (tid >> 4);          // k within tile
        int cq = tid & 15;                      // 4-col chunk
        f32x4 v = *(const f32x4*)(src + (size_t)(k0 + r) * EO_ + n0 + cq * 4);
        #pragma unroll
        for (int i = 0; i < 4; ++i) Ts[cq * 4 + i][r] = f2bf(v[i]);
    }
    __syncthreads();
    #pragma unroll
    for (int it = 0; it < 2; ++it) {            // write transposed, coalesced 16B rows
        int n = it * 32 + (tid >> 3);
        int c = tid & 7;
        s16x8 v = *(const s16x8*)(&Ts[n][c * 8]);
        *(s16x8*)(dst + (size_t)(n0 + n) * EI_ + k0 + c * 8) = v;
    }
    if (bid < 256) {                            // h0 -> bf16 parity-1 buffer
        int j = bid * 256 + tid;
        hbf1[j] = f2bf(h0[j]);
    }
    if (bid == 0 && tid < 64) flags[tid] = 0u;
}

// ---- kernel 1: G = tanh(X @ wxh) into the outs region of d_out (unchanged from R1, passed) ----
__launch_bounds__(256, 2)
__global__ void gemm_g_kernel(const float* __restrict__ X,
                              const unsigned short* __restrict__ WT,
                              float* __restrict__ out)
{
    __shared__ alignas(16) unsigned short As[128 * 72];
    __shared__ alignas(16) unsigned short Bs[128 * 72];

    const int bid = blockIdx.x;
    const int bn = bid & 7, bm = bid >> 3;
    const int m0 = bm * 128, n0 = bn * 128;
    const int tid  = threadIdx.x;
    const int lane = tid & 63, w = tid >> 6;
    const int wr = w >> 1, wc = w & 1;
    const int l15 = lane & 15, lg = lane >> 4;

    f32x4 acc[4][4] = {};

    for (int kt = 0; kt < EI_ / 64; ++kt) {
        const int k0 = kt * 64;
        #pragma unroll
        for (int p = 0; p < 8; ++p) {
            int row = p * 16 + (tid >> 4);
            int kq  = tid & 15;
            f32x4 v = *(const f32x4*)(X + (size_t)(m0 + row) * EI_ + k0 + kq * 4);
            u16x4 hv;
            hv[0] = f2bf(v[0]); hv[1] = f2bf(v[1]); hv[2] = f2bf(v[2]); hv[3] = f2bf(v[3]);
            *(u16x4*)(&As[row * 72 + kq * 4]) = hv;
        }
        #pragma unroll
        for (int p = 0; p < 4; ++p) {
            int n  = p * 32 + (tid >> 3);
            int kq = tid & 7;
            s16x8 v = *(const s16x8*)(WT + (size_t)(n0 + n) * EI_ + k0 + kq * 8);
            *(s16x8*)(&Bs[n * 72 + kq * 8]) = v;
        }
        __syncthreads();
        #pragma unroll
        for (int kk = 0; kk < 2; ++kk) {
            s16x8 a[4], b[4];
            #pragma unroll
            for (int mt = 0; mt < 4; ++mt)
                a[mt] = *(const s16x8*)(&As[(wr * 64 + mt * 16 + l15) * 72 + kk * 32 + lg * 8]);
            #pragma unroll
            for (int nt = 0; nt < 4; ++nt)
                b[nt] = *(const s16x8*)(&Bs[(wc * 64 + nt * 16 + l15) * 72 + kk * 32 + lg * 8]);
            #pragma unroll
            for (int mt = 0; mt < 4; ++mt)
                #pragma unroll
                for (int nt = 0; nt < 4; ++nt)
                    acc[mt][nt] = __builtin_amdgcn_mfma_f32_16x16x32_bf16(a[mt], b[nt], acc[mt][nt], 0, 0, 0);
        }
        __syncthreads();
    }
    #pragma unroll
    for (int mt = 0; mt < 4; ++mt) {
        #pragma unroll
        for (int nt = 0; nt < 4; ++nt) {
            #pragma unroll
            for (int r = 0; r < 4; ++r) {
                int row = wr * 64 + mt * 16 + lg * 4 + r;
                int col = wc * 64 + nt * 16 + l15;
                float s = acc[mt][nt][r];
                float e = __expf(2.f * s);
                out[(size_t)(m0 + row) * EO_ + n0 + col] = 1.f - 2.f / (e + 1.f);
            }
        }
    }
}

// ---- kernel 2: recurrence. 64 blocks x 1024 thr = 4 batch-groups x 16 col-blocks (64 cols).
// whf slice resident in LDS for all 512 steps; fp32 h in registers; cross-block H/flags via
// agent-scope relaxed atomics (sc0 sc1, coherent at L3) -- NO threadfence anywhere.
__launch_bounds__(1024, 1)
__global__ void recur_kernel(const float* __restrict__ h0,
                             const unsigned short* __restrict__ whfT, // whf^T bf16 [N][K]
                             unsigned short* hbf,                     // [2][B_*EO_]
                             unsigned int* flags,                     // [64]
                             float* out)
{
    __shared__ alignas(16) unsigned short Ws[64 * 1024];   // XOR-swizzled [c][k]
    __shared__ float Sred[4 * 16 * 68];                    // [kq][row][col] padded

    const int bid = blockIdx.x;
    const int cb = bid >> 4;          // batch group 0..3
    const int cc = bid & 15;          // col block 0..15
    const int tid = threadIdx.x;
    const int lane = tid & 63, w = tid >> 6;
    const int l15 = lane & 15, lg = lane >> 4;
    const int nq = w & 3, kq = w >> 2;

    // stage W slice once: 64 cols x 1024 k, swizzle k ^= ((c&7)<<3) (16B granules)
    {
        int c  = tid >> 4;
        int k8 = tid & 15;
        #pragma unroll
        for (int p = 0; p < 8; ++p) {
            int k = (k8 + p * 16) * 8;
            s16x8 v = *(const s16x8*)(whfT + (size_t)(cc * 64 + c) * EO_ + k);
            *(s16x8*)(&Ws[c * 1024 + (k ^ ((c & 7) << 3))]) = v;
        }
    }

    const int row = tid >> 6;         // 0..15 (batch within group)
    const int col = tid & 63;         // 0..63 (col within block)
    const int b = cb * 16 + row;
    const int j = cc * 64 + col;
    float h = h0[(size_t)b * EO_ + j];

    const unsigned int* flg = flags + cb * 16;
    const int wc_frag = nq * 16 + l15;                 // W col for this wave's B-frag
    const int ksw = (wc_frag & 7) << 3;

    __syncthreads();

    for (int t = 0; t < T_; ++t) {
        size_t oidx = ((size_t)b * T_ + t) * EO_ + j;
        float g = out[oidx];                           // prefetch g_t (no peer dependence)

        if (t > 0 && w == 0) {                         // only wave 0 polls
            unsigned int want = (unsigned int)t;
            int spins = 0;
            for (;;) {
                unsigned int f = (lane < 16)
                    ? __hip_atomic_load(&flg[lane], __ATOMIC_RELAXED, __HIP_MEMORY_SCOPE_AGENT)
                    : want;
                if (__ballot(f >= want) == ~0ULL) break;
                if (++spins > (1 << 20)) break;        // safety valve
            }
        }
        __syncthreads();

        // S_partial = H_old[16 rows, kq-quarter] @ Ws[nq-tile] ; A via coherent u64 loads
        const unsigned short* arow = hbf + (size_t)((t & 1) ^ 1) * (B_ * EO_)
                                   + (size_t)(cb * 16 + l15) * EO_;
        unsigned long long a0[8], a1[8];
        #pragma unroll
        for (int kk = 0; kk < 8; ++kk) {
            int k = kq * 256 + kk * 32 + lg * 8;
            a0[kk] = __hip_atomic_load((const unsigned long long*)(arow + k),
                                       __ATOMIC_RELAXED, __HIP_MEMORY_SCOPE_AGENT);
            a1[kk] = __hip_atomic_load((const unsigned long long*)(arow + k + 4),
                                       __ATOMIC_RELAXED, __HIP_MEMORY_SCOPE_AGENT);
        }
        f32x4 acc = {0.f, 0.f, 0.f, 0.f};
        #pragma unroll
        for (int kk = 0; kk < 8; ++kk) {
            int k = kq * 256 + kk * 32 + lg * 8;
            s16x8 bb = *(const s16x8*)(&Ws[wc_frag * 1024 + (k ^ ksw)]);
            union { unsigned long long u[2]; s16x8 v; } av;
            av.u[0] = a0[kk]; av.u[1] = a1[kk];
            acc = __builtin_amdgcn_mfma_f32_16x16x32_bf16(av.v, bb, acc, 0, 0, 0);
        }
        #pragma unroll
        for (int r = 0; r < 4; ++r)
            Sred[kq * (16 * 68) + (lg * 4 + r) * 68 + nq * 16 + l15] = acc[r];
        __syncthreads();

        float s = Sred[row * 68 + col]        + Sred[1088 + row * 68 + col]
                + Sred[2176 + row * 68 + col] + Sred[3264 + row * 68 + col];
        float fg = 1.f / (1.f + __expf(-s));
        h = (1.f - fg) * h + fg * g;
        out[oidx] = h;

        unsigned short mybf = f2bf(h);
        unsigned int other = (unsigned int)__shfl_xor((int)(unsigned int)mybf, 1);
        if (!(lane & 1)) {
            unsigned int packed = (unsigned int)mybf | (other << 16);
            __hip_atomic_store((unsigned int*)(hbf + (size_t)(t & 1) * (B_ * EO_)
                                               + (size_t)b * EO_ + j),
                               packed, __ATOMIC_RELAXED, __HIP_MEMORY_SCOPE_AGENT);
        }
        __syncthreads();                               // drains all waves' stores (vmcnt 0)
        if (tid == 0)
            __hip_atomic_store(&flags[cb * 16 + cc], (unsigned int)(t + 1),
                               __ATOMIC_RELAXED, __HIP_MEMORY_SCOPE_AGENT);
    }
    out[(size_t)B_ * T_ * EO_ + (size_t)b * EO_ + j] = h;
}

extern "C" void kernel_launch(void* const* d_in, const int* in_sizes, int n_in,
                              void* d_out, int out_size, void* d_ws, size_t ws_size,
                              hipStream_t stream)
{
    const float* x   = (const float*)d_in[0];
    const float* h0  = (const float*)d_in[1];
    const float* wxh = (const float*)d_in[2];
    const float* whf = (const float*)d_in[3];
    float* out = (float*)d_out;

    char* ws = (char*)d_ws;
    unsigned short* whfT  = (unsigned short*)(ws);
    unsigned short* wxhT  = (unsigned short*)(ws + (size_t)2 * 1024 * 1024);
    unsigned short* hbf   = (unsigned short*)(ws + (size_t)4 * 1024 * 1024);
    unsigned int*   flags = (unsigned int*)  (ws + (size_t)4 * 1024 * 1024 + 512 * 1024);

    prep_kernel<<<512, 256, 0, stream>>>(wxh, whf, h0, wxhT, whfT, hbf + B_ * EO_, flags);
    gemm_g_kernel<<<2048, 256, 0, stream>>>(x, wxhT, out);
    recur_kernel<<<64, 1024, 0, stream>>>(h0, whfT, hbf, flags, out);
}